// Round 5
// baseline (91.224 us; speedup 1.0000x reference)
//
#include <hip/hip_runtime.h>

// TanhAttention: B=4, L=512, D=256
//   scores[b,i,j] = sum_d tanh(H[b,i,d]+H[b,j,d]) * w[d] + bias
//   alpha = softmax_j(scores); r = alpha @ H
// Outputs concatenated: r (524288 floats) then alpha (1048576 floats).
//
// Math: tanh(x) = 1 - 2/(1+e^{2x}); with E = exp2(K*h), K = 2*log2(e):
//   e^{2(hi+hj)} = Ei*Ej  ->  score_shifted = -2*sum_d w_d * rcp(fma(Ei,Ej,1))
// (softmax shift cancels sum(w)+bias -> bias unused; symmetric -> upper tiles only).
//
// R13: 8-wave straight-line score kernel (87.6 total).
// R14: phase-2 waves 4->8 -> Δ=0 (BW-bound). R15: w->SGPR pin -> +1.9 (reverted).
// R16: attribution: T_score ≈ 17.8 (incl gap); score stall-dominated (pipe model ~5-6).
// R17: phase-2 rows/block 4->8: L2 H-traffic 256->128MB -> -1.6 (T2 ≈ 6.5, near floor).
// R18: persistent pipelined score. Grid 512 (exact 2-block/CU residency, 1 round),
//      each block 4-5 tiles (stride 512), ping-pong hvA/hvB: next tile's 4 staging
//      loads issued before current tile's q-loop -> staging latency hidden for all
//      but the first tile; wqa/lane setup amortized. Predict T_score -3..-4.5us.

#define B_ 4
#define L_ 512
#define D_ 256
#define NT16 32         // L_/16
#define NTRI16 528      // 32*33/2 upper-tri 16x16 tiles per batch
#define NTG (B_ * NTRI16)   // 2112 global tiles
#define GRID_S 512      // persistent score blocks (2 blocks/CU, all resident)
#define ST 36           // staging slot stride (dwords): conflict-free, 16B-aligned

typedef float v4f __attribute__((ext_vector_type(4)));

// Decode global tile id -> (b, i0, j0, diff). All block-uniform.
struct TileInfo { int b, i0, j0; bool diff; };

__device__ __forceinline__ TileInfo decodeTile(int g) {
    TileInfo T;
    T.b = g / NTRI16;
    int t = g - T.b * NTRI16;
    // closed-form upper-tri index: n = 32-ti solves n(n+1)/2 >= u, u = 528-t
    int u = NTRI16 - t;
    int n = (int)((__builtin_amdgcn_sqrtf((float)(8 * u + 1)) - 1.0f) * 0.5f);
    while (n * (n + 1) / 2 < u) ++n;         // fp fixup, <=2 iters
    int ti = NT16 - n;
    int tj = ti + (t - (NTRI16 - n * (n + 1) / 2));
    T.i0 = ti * 16; T.j0 = tj * 16;
    T.diff = (ti != tj);
    return T;
}

// Issue the 4 staging loads for a tile (this wave's 32 rows x 32 d slice).
__device__ __forceinline__ void loadTile(const TileInfo& T, const float* H,
                                         int dq0, int lane, float4* hv) {
    const float* Hb = H + (size_t)T.b * L_ * D_;
    #pragma unroll
    for (int s = 0; s < 4; ++s) {
        int idx = lane + 64 * s;
        int r = idx >> 3, q = idx & 7;
        int srow = (r < 16) ? (T.i0 + r) : (T.j0 + r - 16);
        hv[s] = *(const float4*)(Hb + srow * D_ + dq0 + 4 * q);
    }
}

// Full per-tile compute: exp2+stage -> q-loop -> combine -> write (+mirror).
__device__ __forceinline__ void processTile(
    const TileInfo& T, const float4* hv, float* buf,
    float (*pr)[16][17], float (*sc)[17], const float4* wqa,
    int tid, int wv, int lane, int ig, int jg, float* sOut)
{
    const float K = 2.8853900817779268f;     // 2*log2(e)

    #pragma unroll
    for (int s = 0; s < 4; ++s) {
        int idx = lane + 64 * s;
        int r = idx >> 3, q = idx & 7;
        v4f ev;
        ev.x = __builtin_amdgcn_exp2f(hv[s].x * K);
        ev.y = __builtin_amdgcn_exp2f(hv[s].y * K);
        ev.z = __builtin_amdgcn_exp2f(hv[s].z * K);
        ev.w = __builtin_amdgcn_exp2f(hv[s].w * K);
        *(v4f*)&buf[r * ST + 4 * q] = ev;
    }
    __builtin_amdgcn_wave_barrier();         // pin ds_writes before reads (own wave)

    v4f acc[2][2];
    #pragma unroll
    for (int ii = 0; ii < 2; ++ii)
        #pragma unroll
        for (int jj = 0; jj < 2; ++jj) acc[ii][jj] = (v4f){0.f, 0.f, 0.f, 0.f};

    #pragma unroll
    for (int q = 0; q < 8; ++q) {            // 4-d block per step
        v4f wvv; wvv.x = wqa[q].x; wvv.y = wqa[q].y; wvv.z = wqa[q].z; wvv.w = wqa[q].w;
        v4f Ei[2], Ej[2];
        #pragma unroll
        for (int ii = 0; ii < 2; ++ii)       // slots ii*8+ig: all 32 banks once
            Ei[ii] = *(const v4f*)&buf[(ii * 8 + ig) * ST + 4 * q];
        #pragma unroll
        for (int jj = 0; jj < 2; ++jj)
            Ej[jj] = *(const v4f*)&buf[(16 + jj * 8 + jg) * ST + 4 * q];
        #pragma unroll
        for (int ii = 0; ii < 2; ++ii)
            #pragma unroll
            for (int jj = 0; jj < 2; ++jj) {
                v4f den = Ei[ii] * Ej[jj] + 1.0f;
                v4f rr;
                rr.x = __builtin_amdgcn_rcpf(den.x);
                rr.y = __builtin_amdgcn_rcpf(den.y);
                rr.z = __builtin_amdgcn_rcpf(den.z);
                rr.w = __builtin_amdgcn_rcpf(den.w);
                acc[ii][jj] += wvv * rr;
            }
    }

    // ---- partials to LDS ----
    #pragma unroll
    for (int ii = 0; ii < 2; ++ii)
        #pragma unroll
        for (int jj = 0; jj < 2; ++jj) {
            v4f a = acc[ii][jj];
            pr[wv][ig + 8 * ii][jg + 8 * jj] = a.x + a.y + a.z + a.w;
        }
    __syncthreads();

    // ---- combine 8 slices; threads 0..255 own one tile element each ----
    float val = 0.0f;
    const int row = (tid >> 4) & 15, col = tid & 15;
    const size_t sBase = (size_t)T.b * L_ * L_;
    if (tid < 256) {
        #pragma unroll
        for (int k = 0; k < 8; ++k) val += pr[k][row][col];
        val *= -2.0f;                        // shifted score
        sOut[sBase + (size_t)(T.i0 + row) * L_ + T.j0 + col] = val;  // upper, coalesced
    }
    if (T.diff) {                            // mirror via LDS transpose (block-uniform)
        if (tid < 256) sc[row][col] = val;
        __syncthreads();
        if (tid < 256)
            sOut[sBase + (size_t)(T.j0 + row) * L_ + T.i0 + col] = sc[col][row];
    }
    __syncthreads();                         // pr/sc reusable by next tile
}

__global__ __launch_bounds__(512) void score_kernel(
    const float* __restrict__ H, const float* __restrict__ w,
    float* __restrict__ sOut)
{
    __shared__ __align__(16) float lds[8][32 * ST];   // 36.9 KB staging (E values)
    __shared__ float pr[8][16][17];                   // 8.7 KB partial scores
    __shared__ float sc[16][17];                      // 1.1 KB mirror transpose

    const int tid  = threadIdx.x;
    const int wv   = tid >> 6;               // D-slice index 0..7
    const int lane = tid & 63;
    const int dq0  = wv * 32;                // this wave's 32-d slice
    const int ig = lane >> 3, jg = lane & 7; // i = i0+ig+8*ii, j = j0+jg+8*jj
    float* const buf = &lds[wv][0];

    // w-quads: loop-invariant across tiles, load once (VGPR, per R15 lesson)
    float4 wqa[8];
    #pragma unroll
    for (int q = 0; q < 8; ++q)
        wqa[q] = *(const float4*)(w + dq0 + 4 * q);

    // ---- persistent ping-pong pipeline over tiles g, g+512, g+1024, ... ----
    int g = blockIdx.x;                      // 0..511 (< NTG always)
    float4 hvA[4], hvB[4];
    TileInfo TA = decodeTile(g), TB;
    loadTile(TA, H, dq0, lane, hvA);

    while (true) {
        int g2 = g + GRID_S;
        bool p2 = (g2 < NTG);
        if (p2) { TB = decodeTile(g2); loadTile(TB, H, dq0, lane, hvB); }
        processTile(TA, hvA, buf, pr, sc, wqa, tid, wv, lane, ig, jg, sOut);
        if (!p2) break;

        int g3 = g2 + GRID_S;
        bool p3 = (g3 < NTG);
        if (p3) { TA = decodeTile(g3); loadTile(TA, H, dq0, lane, hvA); }
        processTile(TB, hvB, buf, pr, sc, wqa, tid, wv, lane, ig, jg, sOut);
        if (!p3) break;
        g = g3;
    }
}

// Phase 2 (R17, near L2-BW floor): 256 blocks x 512 thr (8 waves); 8 rows/block.
// A: softmax, wave w owns row w. B: r-phase, wave w owns j in [64w,64w+64),
// racc[8]; H[b] once per block (128MB L2 total). C: union'd pr reduce.
union SMem {
    float sc[8][L_];          // 16 KB (phases A,B)
    float pr[8][8][D_];       // 64 KB (phase C)
};

__global__ __launch_bounds__(512) void softmax_r_kernel(
    const float* __restrict__ H, float* __restrict__ rOut, float* __restrict__ aOut)
{
    __shared__ __align__(16) SMem u;

    const int tid  = threadIdx.x;
    const int blk  = blockIdx.x;     // 0..255
    const int b    = blk >> 6;
    const int i0   = (blk & 63) * 8;
    const int wv   = tid >> 6;       // wave 0..7
    const int lane = tid & 63;
    const float* Hb = H + (size_t)b * L_ * D_;
    const float L2E = 1.4426950408889634f;

    // ---- A: softmax, wave wv handles row wv ----
    {
        const int row = wv;
        float* aRow = aOut + ((size_t)b * L_ + i0 + row) * L_;
        float v[8];
        float m = -1e30f;
        #pragma unroll
        for (int k = 0; k < 8; ++k) {
            v[k] = aRow[lane + 64 * k];      // coalesced score reads (L2/L3-hot)
            m = fmaxf(m, v[k]);
        }
        #pragma unroll
        for (int off = 1; off < 64; off <<= 1)
            m = fmaxf(m, __shfl_xor(m, off, 64));
        float s = 0.0f;
        #pragma unroll
        for (int k = 0; k < 8; ++k) {
            v[k] = __builtin_amdgcn_exp2f((v[k] - m) * L2E);
            s += v[k];
        }
        #pragma unroll
        for (int off = 1; off < 64; off <<= 1)
            s += __shfl_xor(s, off, 64);
        const float inv = __builtin_amdgcn_rcpf(s);
        #pragma unroll
        for (int k = 0; k < 8; ++k) {
            float a = v[k] * inv;
            u.sc[row][lane + 64 * k] = a;
            aRow[lane + 64 * k] = a;         // overwrite scores with alpha in place
        }
    }
    __syncthreads();

    // ---- B: r-phase, wave-cooperative over j (64 j per wave), 8 rows ----
    const int jbase = 64 * wv;
    v4f racc[8];
    #pragma unroll
    for (int r = 0; r < 8; ++r) racc[r] = (v4f){0.f, 0.f, 0.f, 0.f};
    const v4f* Hb4 = (const v4f*)Hb;         // [512][64]

    #pragma unroll 2
    for (int js = 0; js < 64; js += 4) {
        v4f h[4];
        #pragma unroll
        for (int q = 0; q < 4; ++q)
            h[q] = Hb4[(size_t)(jbase + js + q) * (D_ / 4) + lane];
        #pragma unroll
        for (int r = 0; r < 8; ++r) {
            v4f av = *(const v4f*)&u.sc[r][jbase + js];   // b128 uniform broadcast
            #pragma unroll
            for (int q = 0; q < 4; ++q)
                racc[r] += av[q] * h[q];
        }
    }
    __syncthreads();                 // all sc reads done before pr overwrites it

    #pragma unroll
    for (int r = 0; r < 8; ++r)
        *(v4f*)&u.pr[wv][r][4 * lane] = racc[r];
    __syncthreads();

    // ---- C: reduce 8 wave-partials, write r (all 512 threads) ----
    {
        const int fq  = tid & 63;        // float4 index in D
        const int row = tid >> 6;        // 0..7
        v4f s = *(const v4f*)&u.pr[0][row][4 * fq];
        #pragma unroll
        for (int k = 1; k < 8; ++k)
            s += *(const v4f*)&u.pr[k][row][4 * fq];
        *(v4f*)&rOut[((size_t)b * L_ + i0 + row) * D_ + 4 * fq] = s;
    }
}

extern "C" void kernel_launch(void* const* d_in, const int* in_sizes, int n_in,
                              void* d_out, int out_size, void* d_ws, size_t ws_size,
                              hipStream_t stream) {
    const float* H = (const float*)d_in[0];
    const float* w = (const float*)d_in[1];
    // d_in[2] (bias) unused: softmax shift-invariance cancels it.
    float* rOut = (float*)d_out;
    float* aOut = rOut + (size_t)B_ * L_ * D_;   // alpha region doubles as score scratch

    score_kernel<<<dim3(GRID_S), 512, 0, stream>>>(H, w, aOut);
    softmax_r_kernel<<<dim3(B_ * (L_ / 8)), 512, 0, stream>>>(H, rOut, aOut);
}

// Round 6
// 85.229 us; speedup vs baseline: 1.0703x; 1.0703x over previous
//
#include <hip/hip_runtime.h>

// TanhAttention: B=4, L=512, D=256
//   scores[b,i,j] = sum_d tanh(H[b,i,d]+H[b,j,d]) * w[d] + bias
//   alpha = softmax_j(scores); r = alpha @ H
// Outputs concatenated: r (524288 floats) then alpha (1048576 floats).
//
// Math: tanh(x) = 1 - 2/(1+e^{2x}); with E = exp2(K*h), K = 2*log2(e):
//   e^{2(hi+hj)} = Ei*Ej  ->  score_shifted = -2*sum_d w_d * rcp(fma(Ei,Ej,1))
// (softmax shift cancels sum(w)+bias -> bias unused; symmetric -> upper tiles only).
//
// R13: 8-wave straight-line score kernel (87.6 total, score ~16-17.8us by R16).
// R14: phase-2 waves 4->8 -> Δ=0 (BW-bound). R15: w->SGPR + pin -> +1.9 (spills
//      and/or readfirstlane chains; pin WITHOUT pressure removal fails).
// R17: phase-2 rows/block 4->8 -> -1.6 (T2 ~6.5, near L2 floor). KEPT.
// R18: persistent 512-block score -> +5.2 REGRESSION. Post-mortem: 512 blocks =
//      2 blocks/CU vs R13's ~3 -> CUT occupancy. Lesson: score IS TLP-sensitive.
// R19: raise score residency the right way. VGPR audit: wqa[8] float4 = 32 regs
//      of loop-invariant data pushes waves to ~100 VGPR -> 2 blocks/CU (VGPR-bound,
//      LDS allowed 3). Move w to per-wave LDS slice (wave-local: no block barrier,
//      uniform broadcast ds_read_b128 per q) + __launch_bounds__(512,6) -> <=85
//      VGPR -> 3 blocks/CU = 24 waves/CU. Predict T_score -2.5..-4 -> dur ~82-84.

#define B_ 4
#define L_ 512
#define D_ 256
#define NT16 32         // L_/16
#define NTRI16 528      // 32*33/2 upper-tri 16x16 tiles per batch
#define ST 36           // staging slot stride (dwords): conflict-free, 16B-aligned

typedef float v4f __attribute__((ext_vector_type(4)));

__global__ __launch_bounds__(512, 6) void score_kernel(
    const float* __restrict__ H, const float* __restrict__ w,
    float* __restrict__ sOut)
{
    __shared__ __align__(16) float lds[8][32 * ST];   // 36.9 KB staging (E values)
    __shared__ float pr[8][16][17];                   // 8.7 KB partial scores
    __shared__ float sc[16][17];                      // 1.1 KB mirror transpose
    __shared__ __align__(16) float wlds[8][32];       // 1 KB per-wave w slices

    const int tid  = threadIdx.x;
    const int wv   = tid >> 6;               // D-slice index 0..7
    const int lane = tid & 63;
    const int blk  = blockIdx.x;             // 0 .. 2111 (one block per (b,tile))
    const int b    = blk / NTRI16;
    const int t    = blk - b * NTRI16;
    // closed-form upper-tri index: n = 32-ti solves n(n+1)/2 >= u, u = 528-t
    const int u  = NTRI16 - t;
    int n = (int)((__builtin_amdgcn_sqrtf((float)(8 * u + 1)) - 1.0f) * 0.5f);
    while (n * (n + 1) / 2 < u) ++n;         // fp fixup, <=2 iters
    const int ti = NT16 - n;
    const int tj = ti + (t - (NTRI16 - n * (n + 1) / 2));
    const int i0 = ti * 16, j0 = tj * 16;
    const int dq0 = wv * 32;                 // this wave's 32-d slice
    const float K = 2.8853900817779268f;     // 2*log2(e)
    const float* Hb = H + (size_t)b * L_ * D_;

    const int ig = lane >> 3, jg = lane & 7; // i = i0+ig+8*ii, j = j0+jg+8*jj

    float* const buf = &lds[wv][0];

    // w slice -> this wave's LDS (wave-local: wave_barrier suffices, no syncthreads)
    if (lane < 32) wlds[wv][lane] = w[dq0 + lane];

    // ---- stage this wave's 32 rows x 32 d: 256 quads / 64 lanes = 4 each ----
    float4 hv[4];
    int slot[4], scol[4];
    #pragma unroll
    for (int s = 0; s < 4; ++s) {
        int idx = lane + 64 * s;
        int r = idx >> 3, q = idx & 7;
        int srow = (r < 16) ? (i0 + r) : (j0 + r - 16);
        slot[s] = r;
        scol[s] = 4 * q;
        hv[s] = *(const float4*)(Hb + srow * D_ + dq0 + 4 * q);   // batched loads
    }
    #pragma unroll
    for (int s = 0; s < 4; ++s) {
        v4f ev;
        ev.x = __builtin_amdgcn_exp2f(hv[s].x * K);
        ev.y = __builtin_amdgcn_exp2f(hv[s].y * K);
        ev.z = __builtin_amdgcn_exp2f(hv[s].z * K);
        ev.w = __builtin_amdgcn_exp2f(hv[s].w * K);
        *(v4f*)&buf[slot[s] * ST + scol[s]] = ev;
    }

    __builtin_amdgcn_wave_barrier();         // pin ds_writes before reads (own wave only)

    v4f acc[2][2];
    #pragma unroll
    for (int ii = 0; ii < 2; ++ii)
        #pragma unroll
        for (int jj = 0; jj < 2; ++jj) acc[ii][jj] = (v4f){0.f, 0.f, 0.f, 0.f};

    #pragma unroll
    for (int q = 0; q < 8; ++q) {            // 4-d block per step
        v4f wvv = *(const v4f*)&wlds[wv][4 * q];   // uniform-address broadcast read
        v4f Ei[2], Ej[2];
        #pragma unroll
        for (int ii = 0; ii < 2; ++ii)       // slots ii*8+ig: all 32 banks once
            Ei[ii] = *(const v4f*)&buf[(ii * 8 + ig) * ST + 4 * q];
        #pragma unroll
        for (int jj = 0; jj < 2; ++jj)
            Ej[jj] = *(const v4f*)&buf[(16 + jj * 8 + jg) * ST + 4 * q];
        #pragma unroll
        for (int ii = 0; ii < 2; ++ii)
            #pragma unroll
            for (int jj = 0; jj < 2; ++jj) {
                v4f den = Ei[ii] * Ej[jj] + 1.0f;
                v4f rr;
                rr.x = __builtin_amdgcn_rcpf(den.x);
                rr.y = __builtin_amdgcn_rcpf(den.y);
                rr.z = __builtin_amdgcn_rcpf(den.z);
                rr.w = __builtin_amdgcn_rcpf(den.w);
                acc[ii][jj] += wvv * rr;
            }
    }

    // ---- partials to LDS ----
    #pragma unroll
    for (int ii = 0; ii < 2; ++ii)
        #pragma unroll
        for (int jj = 0; jj < 2; ++jj) {
            v4f a = acc[ii][jj];
            pr[wv][ig + 8 * ii][jg + 8 * jj] = a.x + a.y + a.z + a.w;
        }
    __syncthreads();

    // ---- combine 8 slices; threads 0..255 own one tile element each ----
    float val = 0.0f;
    const int row = (tid >> 4) & 15, col = tid & 15;
    if (tid < 256) {
        #pragma unroll
        for (int k = 0; k < 8; ++k) val += pr[k][row][col];
        val *= -2.0f;                        // shifted score
        sOut[((size_t)b * L_ + i0 + row) * L_ + j0 + col] = val;   // upper, coalesced
    }
    if (ti != tj) {                          // mirror via LDS transpose (block-uniform)
        if (tid < 256) sc[row][col] = val;
        __syncthreads();
        if (tid < 256)
            sOut[((size_t)b * L_ + j0 + row) * L_ + i0 + col] = sc[col][row];
    }
}

// Phase 2 (R17, near L2-BW floor): 256 blocks x 512 thr (8 waves); 8 rows/block.
// A: softmax, wave w owns row w. B: r-phase, wave w owns j in [64w,64w+64),
// racc[8]; H[b] once per block (128MB L2 total). C: union'd pr reduce.
union SMem {
    float sc[8][L_];          // 16 KB (phases A,B)
    float pr[8][8][D_];       // 64 KB (phase C)
};

__global__ __launch_bounds__(512) void softmax_r_kernel(
    const float* __restrict__ H, float* __restrict__ rOut, float* __restrict__ aOut)
{
    __shared__ __align__(16) SMem u;

    const int tid  = threadIdx.x;
    const int blk  = blockIdx.x;     // 0..255
    const int b    = blk >> 6;
    const int i0   = (blk & 63) * 8;
    const int wv   = tid >> 6;       // wave 0..7
    const int lane = tid & 63;
    const float* Hb = H + (size_t)b * L_ * D_;
    const float L2E = 1.4426950408889634f;

    // ---- A: softmax, wave wv handles row wv ----
    {
        const int row = wv;
        float* aRow = aOut + ((size_t)b * L_ + i0 + row) * L_;
        float v[8];
        float m = -1e30f;
        #pragma unroll
        for (int k = 0; k < 8; ++k) {
            v[k] = aRow[lane + 64 * k];      // coalesced score reads (L2/L3-hot)
            m = fmaxf(m, v[k]);
        }
        #pragma unroll
        for (int off = 1; off < 64; off <<= 1)
            m = fmaxf(m, __shfl_xor(m, off, 64));
        float s = 0.0f;
        #pragma unroll
        for (int k = 0; k < 8; ++k) {
            v[k] = __builtin_amdgcn_exp2f((v[k] - m) * L2E);
            s += v[k];
        }
        #pragma unroll
        for (int off = 1; off < 64; off <<= 1)
            s += __shfl_xor(s, off, 64);
        const float inv = __builtin_amdgcn_rcpf(s);
        #pragma unroll
        for (int k = 0; k < 8; ++k) {
            float a = v[k] * inv;
            u.sc[row][lane + 64 * k] = a;
            aRow[lane + 64 * k] = a;         // overwrite scores with alpha in place
        }
    }
    __syncthreads();

    // ---- B: r-phase, wave-cooperative over j (64 j per wave), 8 rows ----
    const int jbase = 64 * wv;
    v4f racc[8];
    #pragma unroll
    for (int r = 0; r < 8; ++r) racc[r] = (v4f){0.f, 0.f, 0.f, 0.f};
    const v4f* Hb4 = (const v4f*)Hb;         // [512][64]

    #pragma unroll 2
    for (int js = 0; js < 64; js += 4) {
        v4f h[4];
        #pragma unroll
        for (int q = 0; q < 4; ++q)
            h[q] = Hb4[(size_t)(jbase + js + q) * (D_ / 4) + lane];
        #pragma unroll
        for (int r = 0; r < 8; ++r) {
            v4f av = *(const v4f*)&u.sc[r][jbase + js];   // b128 uniform broadcast
            #pragma unroll
            for (int q = 0; q < 4; ++q)
                racc[r] += av[q] * h[q];
        }
    }
    __syncthreads();                 // all sc reads done before pr overwrites it

    #pragma unroll
    for (int r = 0; r < 8; ++r)
        *(v4f*)&u.pr[wv][r][4 * lane] = racc[r];
    __syncthreads();

    // ---- C: reduce 8 wave-partials, write r (all 512 threads) ----
    {
        const int fq  = tid & 63;        // float4 index in D
        const int row = tid >> 6;        // 0..7
        v4f s = *(const v4f*)&u.pr[0][row][4 * fq];
        #pragma unroll
        for (int k = 1; k < 8; ++k)
            s += *(const v4f*)&u.pr[k][row][4 * fq];
        *(v4f*)&rOut[((size_t)b * L_ + i0 + row) * D_ + 4 * fq] = s;
    }
}

extern "C" void kernel_launch(void* const* d_in, const int* in_sizes, int n_in,
                              void* d_out, int out_size, void* d_ws, size_t ws_size,
                              hipStream_t stream) {
    const float* H = (const float*)d_in[0];
    const float* w = (const float*)d_in[1];
    // d_in[2] (bias) unused: softmax shift-invariance cancels it.
    float* rOut = (float*)d_out;
    float* aOut = rOut + (size_t)B_ * L_ * D_;   // alpha region doubles as score scratch

    score_kernel<<<dim3(B_ * NTRI16), 512, 0, stream>>>(H, w, aOut);
    softmax_r_kernel<<<dim3(B_ * (L_ / 8)), 512, 0, stream>>>(H, rOut, aOut);
}